// Round 1
// 533.835 us; speedup vs baseline: 1.0357x; 1.0357x over previous
//
#include <hip/hip_runtime.h>

#define DEV __device__ __forceinline__
typedef unsigned short u16;
typedef unsigned int u32;
typedef __bf16 bf16x8 __attribute__((ext_vector_type(8)));
typedef float f32x4 __attribute__((ext_vector_type(4)));

static constexpr int B = 8192, T = 90, F = 7, H = 128, NOUT = 30;

DEV float fexp2(float x) { return __builtin_amdgcn_exp2f(x); }
DEV float frcp(float x) { return __builtin_amdgcn_rcpf(x); }
DEV float frsq(float x) { return __builtin_amdgcn_rsqf(x); }
DEV float sigm(float x) { return frcp(1.f + fexp2(-1.44269504088896341f * x)); }
DEV u16 f2bfbits(float f) { __bf16 b = (__bf16)f; return __builtin_bit_cast(u16, b); }
DEV float bfbits2f(u32 u) { return __builtin_bit_cast(float, u << 16); }
DEV u32 pk2(float a, float b) { return (u32)f2bfbits(a) | ((u32)f2bfbits(b) << 16); }

DEV float wave_sum(float v) {
#pragma unroll
    for (int m = 32; m; m >>= 1) v += __shfl_xor(v, m, 64);
    return v;
}

// ---------------------------------------------------------------------------
// prep_aux: one 512-thread block.
//   aux[0..6]=m (mean rows of W_in), aux[7]=mean(b_in), aux[8+7c+d]=Q=(W_in^T
//   W_in)/128, aux[64..70]=p=(W_in^T b_in)/128, aux[72]=mean(b_in^2).
//   Uhat[512][32] bf16: cols 0-6 = Wih0 diag(g) W_in, 7 = Wih0 (g.*b_in),
//   8 = Wih0 g, 9 = Wih0 be, 10..31 = 0.  Then layer-1 x-gates = Uhat . z with
//   z = [rstd*x(7), rstd, -rstd*mu, 1, 0...] — exactly Wih0 . LN(W_in x + b_in).
// ---------------------------------------------------------------------------
__global__ __launch_bounds__(512) void prep_aux(
    const float* __restrict__ W_in, const float* __restrict__ b_in,
    const float* __restrict__ g_in, const float* __restrict__ be_in,
    const float* __restrict__ Wih0, float* __restrict__ aux, u16* __restrict__ Uhat) {
    const int tid = threadIdx.x;
    if (tid < 7) {
        float sm = 0.f, sp = 0.f;
        for (int h = 0; h < 128; ++h) { const float w = W_in[h * 7 + tid]; sm += w; sp += w * b_in[h]; }
        aux[tid] = sm * (1.f / 128.f); aux[64 + tid] = sp * (1.f / 128.f);
    } else if (tid < 56) {
        const int cd = tid - 7, cc = cd / 7, dd = cd % 7;
        float s = 0.f;
        for (int h = 0; h < 128; ++h) s += W_in[h * 7 + cc] * W_in[h * 7 + dd];
        aux[8 + cd] = s * (1.f / 128.f);
    } else if (tid == 56) {
        float s = 0.f; for (int h = 0; h < 128; ++h) s += b_in[h];
        aux[7] = s * (1.f / 128.f);
    } else if (tid == 57) {
        float s = 0.f; for (int h = 0; h < 128; ++h) s += b_in[h] * b_in[h];
        aux[72] = s * (1.f / 128.f);
    }
    float acc[10];
#pragma unroll
    for (int i = 0; i < 10; ++i) acc[i] = 0.f;
    const float* wr = Wih0 + (long)tid * 128;
    for (int h = 0; h < 128; ++h) {
        const float wv = wr[h], wg = wv * g_in[h];
#pragma unroll
        for (int cc = 0; cc < 7; ++cc) acc[cc] += wg * W_in[h * 7 + cc];
        acc[7] += wg * b_in[h]; acc[8] += wg; acc[9] += wv * be_in[h];
    }
    u16* dst = Uhat + tid * 32;
#pragma unroll
    for (int cc = 0; cc < 10; ++cc) dst[cc] = f2bfbits(acc[cc]);
#pragma unroll
    for (int cc = 10; cc < 32; ++cc) dst[cc] = 0;
}

// ---------------------------------------------------------------------------
// prep_stats: per (b,t): rstd and -rstd*mu from closed-form mean/var of
// LN input (no 128-wide pass needed). stats[b*T+t] = (rstd, -rstd*mu).
// ---------------------------------------------------------------------------
__global__ __launch_bounds__(256) void prep_stats(
    const float* __restrict__ x, const float* __restrict__ aux,
    float2* __restrict__ stats) {
    __shared__ float sa[80];
    const int tid = threadIdx.x;
    if (tid < 80) sa[tid] = aux[tid];
    __syncthreads();
    const long idx = (long)blockIdx.x * 256 + tid;
    const float* xr = x + idx * 7;
    float xv[7];
#pragma unroll
    for (int cc = 0; cc < 7; ++cc) xv[cc] = xr[cc];
    float mu = sa[7];
#pragma unroll
    for (int cc = 0; cc < 7; ++cc) mu += sa[cc] * xv[cc];
    float q = sa[72];
#pragma unroll
    for (int cc = 0; cc < 7; ++cc) {
        float tacc = 2.f * sa[64 + cc];
#pragma unroll
        for (int dd = 0; dd < 7; ++dd) tacc += sa[8 + cc * 7 + dd] * xv[dd];
        q += xv[cc] * tacc;
    }
    const float rstd = frsq(q - mu * mu + 1e-5f);
    stats[idx] = make_float2(rstd, -rstd * mu);
}

// ---------------------------------------------------------------------------
// Gate math for one accumulator row r. Writes h as bf16 into SHROW.
// References outer-scope: bias[], hwbase.
// ---------------------------------------------------------------------------
#define GATE_R(ACC, CARR, SHROW, R)                                                     \
    {                                                                                   \
        const float xi_ = ACC[0][R] + bias[0];                                          \
        const float xf_ = ACC[1][R] + bias[1];                                          \
        const float xg_ = ACC[2][R] + bias[2];                                          \
        const float xo_ = ACC[3][R] + bias[3];                                          \
        const float tg_ = 2.f * frcp(1.f + fexp2(-2.88539008177792681f * xg_)) - 1.f;   \
        const float cn_ = sigm(xf_) * CARR[R] + sigm(xi_) * tg_;                        \
        CARR[R] = cn_;                                                                  \
        const float so_ = sigm(xo_);                                                    \
        const float rr_ = frcp(1.f + fexp2(-2.88539008177792681f * cn_));               \
        SHROW[hwbase + (R) * 8] = f2bfbits(__builtin_fmaf(2.f * so_, rr_, -so_));       \
    }

// ---------------------------------------------------------------------------
// Layer-1 LSTM: x-side is the K=32 augmented-z MFMA (1 MFMA vs 4), h-side
// K=128. 512 thr / 32 rows / grid 256.
// R1 change: parity-split LDS objects + time-unroll-2 (static parity) so the
// scheduler can PROVE tile-1 ds_reads don't alias tile-0 h ds_writes; tile-1
// MFMA chains are source-interleaved with tile-0 gate math so the
// transcendental burst runs in the matrix-pipe shadow.
// ---------------------------------------------------------------------------
__global__ __launch_bounds__(512, 2) void lstm_rec_l1(
    const float* __restrict__ x, const float2* __restrict__ stats,
    const u16* __restrict__ Uhat, const float* __restrict__ Whh,
    const float* __restrict__ bih, const float* __restrict__ bhh,
    u16* __restrict__ hs) {
    __shared__ __align__(16) u16 s_zA[2][4][16][8];   // [mt][kk8][m][8] 2 KB
    __shared__ __align__(16) u16 s_zB[2][4][16][8];
    __shared__ __align__(16) u16 s_hA[2][16 * 128];   // [mt][chunks] 8 KB
    __shared__ __align__(16) u16 s_hB[2][16 * 128];

    const int tid = threadIdx.x;
    const int wave = tid >> 6, lane = tid & 63, quad = lane >> 4, n16 = lane & 15;
    const int b0 = blockIdx.x * 32;

    for (int i = tid; i < 2 * 4 * 16 * 8; i += 512) { ((u16*)s_zA)[i] = 0; ((u16*)s_zB)[i] = 0; }
    for (int i = tid; i < 2 * 16 * 128; i += 512) ((u16*)s_hB)[i] = 0;

    bf16x8 bU[4], bWhh[4][4];
    float bias[4];
#pragma unroll
    for (int g = 0; g < 4; ++g) {
        const int wrow = g * 128 + 16 * wave + n16;
        bias[g] = bih[wrow] + bhh[wrow];
        bU[g] = *(const bf16x8*)&Uhat[wrow * 32 + quad * 8];
#pragma unroll
        for (int kk = 0; kk < 4; ++kk) {
            const float* ph = Whh + (long)wrow * 128 + kk * 32 + quad * 8;
            bf16x8 bh;
#pragma unroll
            for (int j = 0; j < 8; ++j) bh[j] = (__bf16)ph[j];
            bWhh[g][kk] = bh;
        }
    }

    const f32x4 zero4 = {0.f, 0.f, 0.f, 0.f};
    float c[2][4];
#pragma unroll
    for (int mt = 0; mt < 2; ++mt)
#pragma unroll
        for (int r = 0; r < 4; ++r) c[mt][r] = 0.f;

    // staging: 8 lanes/wave (balanced), 64 units total cover 32 rows x 2 chunks
    const bool stager = (lane < 8);
    const int tau = wave * 8 + lane;
    const int srow = tau & 31, skk8 = tau >> 5;
    const int smt = srow >> 4, sm = srow & 15;
    const long srowg = (long)(b0 + srow) * T;

    // flush map: 512 thr x uint4 cover both 16x128 tiles
    const int ftile = tid >> 8, finner = tid & 255;
    const int fm = finner & 15, fkk8 = finner >> 4;
    const int fldsoff = (fkk8 * 16 + fm) * 8;
    const size_t fgrow = (size_t)(b0 + ftile * 16 + fm) * T;
    const int fgcol = fkk8 * 8;

    const int hwbase = (2 * wave + (n16 >> 3)) * 128 + quad * 32 + (n16 & 7);

    __syncthreads();  // zero-init visible before prologue staging stores

    if (stager) {  // stage z(0) into the A buffer
        const float2 st0 = stats[srowg];
        u32 p0, p1, p2, p3;
        if (skk8 == 0) {
            const float* xp = x + srowg * 7;
            const float rs = st0.x;
            p0 = pk2(rs * xp[0], rs * xp[1]); p1 = pk2(rs * xp[2], rs * xp[3]);
            p2 = pk2(rs * xp[4], rs * xp[5]); p3 = pk2(rs * xp[6], rs);
        } else { p0 = pk2(st0.y, 1.f); p1 = 0; p2 = 0; p3 = 0; }
        *(uint4*)&s_zA[smt][skk8][sm][0] = (uint4){p0, p1, p2, p3};
    }
    __syncthreads();

#define L1_CHAIN_G(AZ, AH, G, OUT)                                                      \
    {                                                                                   \
        f32x4 a_ = __builtin_amdgcn_mfma_f32_16x16x32_bf16(AZ, bU[G], zero4, 0, 0, 0);  \
        a_ = __builtin_amdgcn_mfma_f32_16x16x32_bf16(AH[0], bWhh[G][0], a_, 0, 0, 0);   \
        a_ = __builtin_amdgcn_mfma_f32_16x16x32_bf16(AH[1], bWhh[G][1], a_, 0, 0, 0);   \
        a_ = __builtin_amdgcn_mfma_f32_16x16x32_bf16(AH[2], bWhh[G][2], a_, 0, 0, 0);   \
        a_ = __builtin_amdgcn_mfma_f32_16x16x32_bf16(AH[3], bWhh[G][3], a_, 0, 0, 0);   \
        OUT = a_;                                                                       \
    }

#define L1_STEP(TT, SZR, SZW, SHR, SHW)                                                 \
    {                                                                                   \
        const int t_ = (TT);                                                            \
        const bool hasPre = stager && (t_ + 1 < T);                                     \
        float2 nst = {};                                                                \
        float nx[7];                                                                    \
        if (hasPre) {                                                                   \
            nst = stats[srowg + t_ + 1];                                                \
            if (skk8 == 0) {                                                            \
                const float* xp = x + (srowg + t_ + 1) * 7;                             \
                _Pragma("unroll") for (int j = 0; j < 7; ++j) nx[j] = xp[j];            \
            }                                                                           \
        }                                                                               \
        if (t_ > 0) {  /* flush h(t-1) from the read-side buffer */                     \
            const uint4 hv_ = *(const uint4*)&SHR[ftile][fldsoff];                      \
            *(uint4*)(hs + (fgrow + (t_ - 1)) * 128 + fgcol) = hv_;                     \
        }                                                                               \
        bf16x8 az0, ah0[4];                                                             \
        az0 = *(const bf16x8*)&SZR[0][quad][n16][0];                                    \
        _Pragma("unroll") for (int kk = 0; kk < 4; ++kk)                                \
            ah0[kk] = *(const bf16x8*)&SHR[0][(kk * 4 + quad) * 128 + n16 * 8];         \
        f32x4 acc0[4], acc1[4];                                                         \
        L1_CHAIN_G(az0, ah0, 0, acc0[0])                                                \
        L1_CHAIN_G(az0, ah0, 1, acc0[1])                                                \
        L1_CHAIN_G(az0, ah0, 2, acc0[2])                                                \
        L1_CHAIN_G(az0, ah0, 3, acc0[3])                                                \
        bf16x8 az1, ah1[4];                                                             \
        az1 = *(const bf16x8*)&SZR[1][quad][n16][0];                                    \
        _Pragma("unroll") for (int kk = 0; kk < 4; ++kk)                                \
            ah1[kk] = *(const bf16x8*)&SHR[1][(kk * 4 + quad) * 128 + n16 * 8];         \
        L1_CHAIN_G(az1, ah1, 0, acc1[0])                                                \
        GATE_R(acc0, c[0], SHW[0], 0)                                                   \
        L1_CHAIN_G(az1, ah1, 1, acc1[1])                                                \
        GATE_R(acc0, c[0], SHW[0], 1)                                                   \
        L1_CHAIN_G(az1, ah1, 2, acc1[2])                                                \
        GATE_R(acc0, c[0], SHW[0], 2)                                                   \
        L1_CHAIN_G(az1, ah1, 3, acc1[3])                                                \
        GATE_R(acc0, c[0], SHW[0], 3)                                                   \
        GATE_R(acc1, c[1], SHW[1], 0)                                                   \
        GATE_R(acc1, c[1], SHW[1], 1)                                                   \
        GATE_R(acc1, c[1], SHW[1], 2)                                                   \
        GATE_R(acc1, c[1], SHW[1], 3)                                                   \
        if (hasPre) {  /* commit z(t+1) */                                              \
            u32 p0_, p1_, p2_, p3_;                                                     \
            if (skk8 == 0) {                                                            \
                const float rs_ = nst.x;                                                \
                p0_ = pk2(rs_ * nx[0], rs_ * nx[1]); p1_ = pk2(rs_ * nx[2], rs_ * nx[3]); \
                p2_ = pk2(rs_ * nx[4], rs_ * nx[5]); p3_ = pk2(rs_ * nx[6], rs_);       \
            } else { p0_ = pk2(nst.y, 1.f); p1_ = 0; p2_ = 0; p3_ = 0; }                \
            *(uint4*)&SZW[smt][skk8][sm][0] = (uint4){p0_, p1_, p2_, p3_};              \
        }                                                                               \
        __syncthreads();                                                                \
    }

#pragma unroll 1
    for (int t = 0; t < T; t += 2) {
        L1_STEP(t, s_zA, s_zB, s_hB, s_hA)        // even t: read z A / h B, write h A
        L1_STEP(t + 1, s_zB, s_zA, s_hA, s_hB)    // odd t: roles swapped
    }
#undef L1_STEP
#undef L1_CHAIN_G
    {  // epilogue: h(T-1) was written at odd parity -> s_hB
        const uint4 hv = *(const uint4*)&s_hB[ftile][fldsoff];
        *(uint4*)(hs + (fgrow + (T - 1)) * 128 + fgcol) = hv;
    }
}

// ---------------------------------------------------------------------------
// Layer-2 LSTM: input hs0 [B,T,128] bf16 (full K=128 both sides). Same
// parity-split + interleave restructure; writes only hlast.
// ---------------------------------------------------------------------------
__global__ __launch_bounds__(512, 2) void lstm_rec_l2(
    const float* __restrict__ Wih, const float* __restrict__ Whh,
    const float* __restrict__ bih, const float* __restrict__ bhh,
    const u16* __restrict__ xin, u16* __restrict__ hlast) {
    __shared__ __align__(16) u16 s_xA[2][16 * 128];
    __shared__ __align__(16) u16 s_xB[2][16 * 128];
    __shared__ __align__(16) u16 s_hA[2][16 * 128];
    __shared__ __align__(16) u16 s_hB[2][16 * 128];

    const int tid = threadIdx.x;
    const int wave = tid >> 6, lane = tid & 63, quad = lane >> 4, n16 = lane & 15;
    const int b0 = blockIdx.x * 32;

    for (int i = tid; i < 2 * 16 * 128; i += 512) ((u16*)s_hB)[i] = 0;

    bf16x8 bWih[4][4], bWhh[4][4];
    float bias[4];
#pragma unroll
    for (int g = 0; g < 4; ++g) {
        const int wrow = g * 128 + 16 * wave + n16;
        bias[g] = bih[wrow] + bhh[wrow];
#pragma unroll
        for (int kk = 0; kk < 4; ++kk) {
            const float* pi = Wih + (long)wrow * 128 + kk * 32 + quad * 8;
            const float* ph = Whh + (long)wrow * 128 + kk * 32 + quad * 8;
            bf16x8 bi, bh;
#pragma unroll
            for (int j = 0; j < 8; ++j) { bi[j] = (__bf16)pi[j]; bh[j] = (__bf16)ph[j]; }
            bWih[g][kk] = bi; bWhh[g][kk] = bh;
        }
    }

    const f32x4 zero4 = {0.f, 0.f, 0.f, 0.f};
    float c[2][4];
#pragma unroll
    for (int mt = 0; mt < 2; ++mt)
#pragma unroll
        for (int r = 0; r < 4; ++r) c[mt][r] = 0.f;

    const int stile = tid >> 8, sinner = tid & 255;
    const int sm = sinner & 15, skk8 = sinner >> 4;
    const u16* gsrc = xin + (size_t)(b0 + stile * 16 + sm) * T * 128 + skk8 * 8;
    const int ftile = tid >> 8, finner = tid & 255;
    const int fm = finner & 15, fkk8 = finner >> 4;
    const int fldsoff = (fkk8 * 16 + fm) * 8;
    const int fgcol = fkk8 * 8;

    const int hwbase = (2 * wave + (n16 >> 3)) * 128 + quad * 32 + (n16 & 7);

    {
        const uint4 v = *(const uint4*)gsrc;
        *(uint4*)&s_xA[stile][sinner * 8] = v;
    }
    __syncthreads();

#define L2_CHAIN_G(ALN, AH, G, OUT)                                                     \
    {                                                                                   \
        f32x4 a_ = __builtin_amdgcn_mfma_f32_16x16x32_bf16(ALN[0], bWih[G][0], zero4, 0, 0, 0); \
        a_ = __builtin_amdgcn_mfma_f32_16x16x32_bf16(AH[0], bWhh[G][0], a_, 0, 0, 0);   \
        a_ = __builtin_amdgcn_mfma_f32_16x16x32_bf16(ALN[1], bWih[G][1], a_, 0, 0, 0);  \
        a_ = __builtin_amdgcn_mfma_f32_16x16x32_bf16(AH[1], bWhh[G][1], a_, 0, 0, 0);   \
        a_ = __builtin_amdgcn_mfma_f32_16x16x32_bf16(ALN[2], bWih[G][2], a_, 0, 0, 0);  \
        a_ = __builtin_amdgcn_mfma_f32_16x16x32_bf16(AH[2], bWhh[G][2], a_, 0, 0, 0);   \
        a_ = __builtin_amdgcn_mfma_f32_16x16x32_bf16(ALN[3], bWih[G][3], a_, 0, 0, 0);  \
        a_ = __builtin_amdgcn_mfma_f32_16x16x32_bf16(AH[3], bWhh[G][3], a_, 0, 0, 0);   \
        OUT = a_;                                                                       \
    }

#define L2_STEP(TT, SXR, SXW, SHR, SHW)                                                 \
    {                                                                                   \
        const int t_ = (TT);                                                            \
        const bool hasPre = (t_ + 1 < T);                                               \
        uint4 pre = {};                                                                 \
        if (hasPre) pre = *(const uint4*)(gsrc + (size_t)(t_ + 1) * 128);               \
        bf16x8 aln0[4], ah0[4];                                                         \
        _Pragma("unroll") for (int kk = 0; kk < 4; ++kk) {                              \
            const int ro = (kk * 4 + quad) * 128 + n16 * 8;                             \
            aln0[kk] = *(const bf16x8*)&SXR[0][ro];                                     \
            ah0[kk] = *(const bf16x8*)&SHR[0][ro];                                      \
        }                                                                               \
        f32x4 acc0[4], acc1[4];                                                         \
        L2_CHAIN_G(aln0, ah0, 0, acc0[0])                                               \
        L2_CHAIN_G(aln0, ah0, 1, acc0[1])                                               \
        L2_CHAIN_G(aln0, ah0, 2, acc0[2])                                               \
        L2_CHAIN_G(aln0, ah0, 3, acc0[3])                                               \
        bf16x8 aln1[4], ah1[4];                                                         \
        _Pragma("unroll") for (int kk = 0; kk < 4; ++kk) {                              \
            const int ro = (kk * 4 + quad) * 128 + n16 * 8;                             \
            aln1[kk] = *(const bf16x8*)&SXR[1][ro];                                     \
            ah1[kk] = *(const bf16x8*)&SHR[1][ro];                                      \
        }                                                                               \
        L2_CHAIN_G(aln1, ah1, 0, acc1[0])                                               \
        GATE_R(acc0, c[0], SHW[0], 0)                                                   \
        L2_CHAIN_G(aln1, ah1, 1, acc1[1])                                               \
        GATE_R(acc0, c[0], SHW[0], 1)                                                   \
        L2_CHAIN_G(aln1, ah1, 2, acc1[2])                                               \
        GATE_R(acc0, c[0], SHW[0], 2)                                                   \
        L2_CHAIN_G(aln1, ah1, 3, acc1[3])                                               \
        GATE_R(acc0, c[0], SHW[0], 3)                                                   \
        GATE_R(acc1, c[1], SHW[1], 0)                                                   \
        GATE_R(acc1, c[1], SHW[1], 1)                                                   \
        GATE_R(acc1, c[1], SHW[1], 2)                                                   \
        GATE_R(acc1, c[1], SHW[1], 3)                                                   \
        if (hasPre) *(uint4*)&SXW[stile][sinner * 8] = pre;                             \
        __syncthreads();                                                                \
    }

#pragma unroll 1
    for (int t = 0; t < T; t += 2) {
        L2_STEP(t, s_xA, s_xB, s_hB, s_hA)        // even t
        L2_STEP(t + 1, s_xB, s_xA, s_hA, s_hB)    // odd t
    }
#undef L2_STEP
#undef L2_CHAIN_G
    {  // h(T-1) written at odd parity -> s_hB
        const uint4 hv = *(const uint4*)&s_hB[ftile][fldsoff];
        *(uint4*)(hlast + (size_t)(b0 + ftile * 16 + fm) * 128 + fgcol) = hv;
    }
}

// ---------------------------------------------------------------------------
// Head: 4 rows per wave, 16 rows per block, grid 512.
// ---------------------------------------------------------------------------
__global__ __launch_bounds__(256) void dense_head(
    const u16* __restrict__ hlast, const float* __restrict__ g_ln,
    const float* __restrict__ be_ln, const float* __restrict__ W_d1,
    const float* __restrict__ b_d1, const float* __restrict__ W_d2,
    const float* __restrict__ b_d2, const float* __restrict__ W_d3,
    const float* __restrict__ b_d3, float* __restrict__ out) {
    __shared__ float s_ln[16][128];
    __shared__ float s_d1[16][128];
    __shared__ float s_d2[16][64];
    const int wave = threadIdx.x >> 6, lane = threadIdx.x & 63;
    const long base = (long)blockIdx.x * 16;
    const int R = wave * 4;

#pragma unroll
    for (int rr = 0; rr < 4; ++rr) {
        const long row = base + R + rr;
        const u32 packed = ((const u32*)hlast)[row * 64 + lane];
        float v0 = bfbits2f(packed & 0xffffu), v1 = bfbits2f(packed >> 16);
        const float s = wave_sum(v0 + v1);
        const float q = wave_sum(v0 * v0 + v1 * v1);
        const float mu = s * (1.f / 128.f);
        const float rstd = frsq(q * (1.f / 128.f) - mu * mu + 1e-5f);
        const int h0 = 2 * lane;
        s_ln[R + rr][h0] = (v0 - mu) * rstd * g_ln[h0] + be_ln[h0];
        s_ln[R + rr][h0 + 1] = (v1 - mu) * rstd * g_ln[h0 + 1] + be_ln[h0 + 1];
    }
    __syncthreads();

#pragma unroll
    for (int half = 0; half < 2; ++half) {
        const int o = lane + 64 * half;
        float a[4] = {b_d1[o], b_d1[o], b_d1[o], b_d1[o]};
        const float4* wr = (const float4*)(W_d1 + (long)o * 128);
#pragma unroll 8
        for (int k = 0; k < 32; ++k) {
            const float4 wv = wr[k];
#pragma unroll
            for (int rr = 0; rr < 4; ++rr) {
                const float4 xv = ((const float4*)s_ln[R + rr])[k];
                a[rr] += wv.x * xv.x + wv.y * xv.y + wv.z * xv.z + wv.w * xv.w;
            }
        }
#pragma unroll
        for (int rr = 0; rr < 4; ++rr) s_d1[R + rr][o] = fmaxf(a[rr], 0.f);
    }
    __syncthreads();

    {
        float a[4] = {b_d2[lane], b_d2[lane], b_d2[lane], b_d2[lane]};
        const float4* wr = (const float4*)(W_d2 + (long)lane * 128);
#pragma unroll 8
        for (int k = 0; k < 32; ++k) {
            const float4 wv = wr[k];
#pragma unroll
            for (int rr = 0; rr < 4; ++rr) {
                const float4 xv = ((const float4*)s_d1[R + rr])[k];
                a[rr] += wv.x * xv.x + wv.y * xv.y + wv.z * xv.z + wv.w * xv.w;
            }
        }
#pragma unroll
        for (int rr = 0; rr < 4; ++rr) s_d2[R + rr][lane] = fmaxf(a[rr], 0.f);
    }
    __syncthreads();

    if (lane < NOUT) {
        float a[4] = {b_d3[lane], b_d3[lane], b_d3[lane], b_d3[lane]};
        const float4* wr = (const float4*)(W_d3 + (long)lane * 64);
#pragma unroll
        for (int k = 0; k < 16; ++k) {
            const float4 wv = wr[k];
#pragma unroll
            for (int rr = 0; rr < 4; ++rr) {
                const float4 xv = ((const float4*)s_d2[R + rr])[k];
                a[rr] += wv.x * xv.x + wv.y * xv.y + wv.z * xv.z + wv.w * xv.w;
            }
        }
#pragma unroll
        for (int rr = 0; rr < 4; ++rr) out[(base + R + rr) * NOUT + lane] = a[rr];
    }
}

// ---------------------------------------------------------------------------
extern "C" void kernel_launch(void* const* d_in, const int* in_sizes, int n_in,
                              void* d_out, int out_size, void* d_ws, size_t ws_size,
                              hipStream_t stream) {
    const float* x = (const float*)d_in[0];
    const float* W_in = (const float*)d_in[1];
    const float* b_in = (const float*)d_in[2];
    const float* g_in = (const float*)d_in[3];
    const float* be_in = (const float*)d_in[4];
    const float* Wih0 = (const float*)d_in[5];
    const float* Whh0 = (const float*)d_in[6];
    const float* bih0 = (const float*)d_in[7];
    const float* bhh0 = (const float*)d_in[8];
    const float* Wih1 = (const float*)d_in[9];
    const float* Whh1 = (const float*)d_in[10];
    const float* bih1 = (const float*)d_in[11];
    const float* bhh1 = (const float*)d_in[12];
    const float* g_ln = (const float*)d_in[13];
    const float* be_ln = (const float*)d_in[14];
    const float* W_d1 = (const float*)d_in[15];
    const float* b_d1 = (const float*)d_in[16];
    const float* W_d2 = (const float*)d_in[17];
    const float* b_d2 = (const float*)d_in[18];
    const float* W_d3 = (const float*)d_in[19];
    const float* b_d3 = (const float*)d_in[20];
    float* out = (float*)d_out;

    // workspace layout (~197 MB): aux | Uhat | stats | hs0 | hlast
    char* w = (char*)d_ws;
    float* aux = (float*)w;               w += 512;
    u16* Uhat = (u16*)w;                  w += 512 * 32 * sizeof(u16);
    float2* stats = (float2*)w;           w += (size_t)B * T * sizeof(float2);
    u16* hs0 = (u16*)w;                   w += (size_t)B * T * H * sizeof(u16);
    u16* hlast = (u16*)w;

    prep_aux<<<1, 512, 0, stream>>>(W_in, b_in, g_in, be_in, Wih0, aux, Uhat);
    prep_stats<<<(B * T) / 256, 256, 0, stream>>>(x, aux, stats);
    lstm_rec_l1<<<B / 32, 512, 0, stream>>>(x, stats, Uhat, Whh0, bih0, bhh0, hs0);
    lstm_rec_l2<<<B / 32, 512, 0, stream>>>(Wih1, Whh1, bih1, bhh1, hs0, hlast);
    dense_head<<<B / 16, 256, 0, stream>>>(hlast, g_ln, be_ln, W_d1, b_d1, W_d2, b_d2,
                                           W_d3, b_d3, out);
}